// Round 1
// baseline (266.315 us; speedup 1.0000x reference)
//
#include <hip/hip_runtime.h>
#include <math.h>

// Problem constants (B=1)
#define S 2048
#define DM 512
#define WIN 64
// D = DM/NHEAD = 32 -> scale = 1/sqrt(32)
#define ATTN_SCALE 0.17677669529663687f

// ---------------------------------------------------------------------------
// GEMM: C[M,N] = A[M,K] * B[N,K]^T   (both row-major, K contiguous for both)
// 64x64 tile, BK=16, 256 threads, 4x4 outputs per thread.
// ---------------------------------------------------------------------------
#define TS 64
#define BK 16

__global__ __launch_bounds__(256) void gemm_abt(
    const float* __restrict__ A, const float* __restrict__ B,
    float* __restrict__ C, int M, int N, int K) {
  __shared__ float As[BK][TS + 1];
  __shared__ float Bs[BK][TS + 1];

  const int tx = threadIdx.x & 15;        // 0..15 -> N direction
  const int ty = threadIdx.x >> 4;        // 0..15 -> M direction
  const int row0 = blockIdx.y * TS;
  const int col0 = blockIdx.x * TS;

  // Cooperative load mapping: 256 threads, 64x16 tile = 1024 floats = 4/thread
  const int lm = threadIdx.x >> 2;        // 0..63 row within tile
  const int lk = (threadIdx.x & 3) * 4;   // 0,4,8,12 k offset (float4)

  float acc[4][4] = {};

  for (int k0 = 0; k0 < K; k0 += BK) {
    float4 a4 = *(const float4*)&A[(size_t)(row0 + lm) * K + k0 + lk];
    float4 b4 = *(const float4*)&B[(size_t)(col0 + lm) * K + k0 + lk];
    As[lk + 0][lm] = a4.x; As[lk + 1][lm] = a4.y;
    As[lk + 2][lm] = a4.z; As[lk + 3][lm] = a4.w;
    Bs[lk + 0][lm] = b4.x; Bs[lk + 1][lm] = b4.y;
    Bs[lk + 2][lm] = b4.z; Bs[lk + 3][lm] = b4.w;
    __syncthreads();

#pragma unroll
    for (int kk = 0; kk < BK; ++kk) {
      float a[4], b[4];
#pragma unroll
      for (int i = 0; i < 4; ++i) a[i] = As[kk][ty * 4 + i];
#pragma unroll
      for (int j = 0; j < 4; ++j) b[j] = Bs[kk][tx * 4 + j];
#pragma unroll
      for (int i = 0; i < 4; ++i)
#pragma unroll
        for (int j = 0; j < 4; ++j) acc[i][j] += a[i] * b[j];
    }
    __syncthreads();
  }

#pragma unroll
  for (int i = 0; i < 4; ++i) {
    float4 r = make_float4(acc[i][0], acc[i][1], acc[i][2], acc[i][3]);
    *(float4*)&C[(size_t)(row0 + ty * 4 + i) * N + col0 + tx * 4] = r;
  }
}

// ---------------------------------------------------------------------------
// Sliding-window per-channel softmax attention.
// For each (i, c): out[i,c] = sum_j softmax_j(q[i,c]*k[j,c]*scale) * v[j,c],
// j in [max(0, i-63), i]. One block per row i, 512 threads = channels.
// ---------------------------------------------------------------------------
__global__ __launch_bounds__(512) void swin_attn(
    const float* __restrict__ q, const float* __restrict__ k,
    const float* __restrict__ v, float* __restrict__ o) {
  const int i = blockIdx.x;
  const int c = threadIdx.x;

  const float qv = q[(size_t)i * DM + c] * ATTN_SCALE;
  const int j0 = (i - WIN + 1) > 0 ? (i - WIN + 1) : 0;

  float m = -INFINITY;
  float l = 0.f;
  float acc = 0.f;
  for (int j = j0; j <= i; ++j) {
    const float kv = k[(size_t)j * DM + c];
    const float vv = v[(size_t)j * DM + c];
    const float s = qv * kv;
    const float mn = fmaxf(m, s);
    const float corr = __expf(m - mn);   // exp(-inf)=0 on first iter
    const float p = __expf(s - mn);
    l = l * corr + p;
    acc = acc * corr + p * vv;
    m = mn;
  }
  o[(size_t)i * DM + c] = acc / l;
}

// ---------------------------------------------------------------------------
// Launch
// ---------------------------------------------------------------------------
extern "C" void kernel_launch(void* const* d_in, const int* in_sizes, int n_in,
                              void* d_out, int out_size, void* d_ws, size_t ws_size,
                              hipStream_t stream) {
  const float* x  = (const float*)d_in[0];
  const float* Wq = (const float*)d_in[1];
  const float* Wk = (const float*)d_in[2];
  const float* Wv = (const float*)d_in[3];
  const float* Wo = (const float*)d_in[4];
  float* out = (float*)d_out;

  // Workspace layout: q, k, v, attn_out each S*DM floats (4 MB each)
  float* q    = (float*)d_ws;
  float* k    = q + (size_t)S * DM;
  float* v    = k + (size_t)S * DM;
  float* attn = v + (size_t)S * DM;

  dim3 gblk(256);
  dim3 ggrid(DM / TS, S / TS);   // (8, 32)

  gemm_abt<<<ggrid, gblk, 0, stream>>>(x, Wq, q, S, DM, DM);
  gemm_abt<<<ggrid, gblk, 0, stream>>>(x, Wk, k, S, DM, DM);
  gemm_abt<<<ggrid, gblk, 0, stream>>>(x, Wv, v, S, DM, DM);

  swin_attn<<<dim3(S), dim3(DM), 0, stream>>>(q, k, v, attn);

  gemm_abt<<<ggrid, gblk, 0, stream>>>(attn, Wo, out, S, DM, DM);
}

// Round 3
// 110.566 us; speedup vs baseline: 2.4087x; 2.4087x over previous
//
#include <hip/hip_runtime.h>
#include <math.h>

// Problem constants (B=1)
#define S 2048
#define DM 512
#define WIN 64
#define ATTN_SCALE 0.17677669529663687f   // 1/sqrt(32)

typedef __attribute__((ext_vector_type(8))) short short8;   // 8 x bf16 (4 VGPR)
typedef __attribute__((ext_vector_type(4))) float floatx4;  // MFMA acc

__device__ __forceinline__ unsigned short f2bf(float f) {
  unsigned int u = __float_as_uint(f);
  unsigned int r = (u + 0x7FFFu + ((u >> 16) & 1u)) >> 16;   // RNE
  return (unsigned short)r;
}

// ---------------------------------------------------------------------------
// Convert x (S*DM floats) and Wq|Wk|Wv|Wo (4 * DM*DM) to bf16.
// ---------------------------------------------------------------------------
__global__ __launch_bounds__(256) void convert_bf16(
    const float* __restrict__ x, const float* __restrict__ Wq,
    const float* __restrict__ Wk, const float* __restrict__ Wv,
    const float* __restrict__ Wo,
    unsigned short* __restrict__ xbf, unsigned short* __restrict__ wbf) {
  size_t i4 = ((size_t)blockIdx.x * 256 + threadIdx.x) * 4;
  const float* src; unsigned short* dst; size_t off;
  const size_t NX = (size_t)S * DM;           // 1,048,576
  if (i4 < NX) {
    src = x; dst = xbf; off = i4;
  } else {
    size_t r = i4 - NX;
    int wsel = (int)(r >> 18);                // / (512*512)
    src = wsel == 0 ? Wq : wsel == 1 ? Wk : wsel == 2 ? Wv : Wo;
    dst = wbf + ((size_t)wsel << 18);
    off = r & 262143;
  }
  float4 f = *(const float4*)(src + off);
  ushort4 o;
  o.x = f2bf(f.x); o.y = f2bf(f.y); o.z = f2bf(f.z); o.w = f2bf(f.w);
  *(ushort4*)(dst + off) = o;
}

// ---------------------------------------------------------------------------
// bf16 MFMA GEMM: C[M,N] = A[M,K] * B[N,K]^T  (fp32 accumulate/output).
// 64x64 block tile, BK=64, 256 threads = 4 waves in 2x2, each wave 32x32
// via 2x2 of mfma_f32_16x16x32_bf16. blockIdx.z selects B/C plane (QKV).
// LDS granule XOR-swizzle: row r, 16B-granule g stored at g ^ (r & 7).
// ---------------------------------------------------------------------------
__global__ __launch_bounds__(256) void gemm_bf16(
    const unsigned short* __restrict__ Abf,
    const unsigned short* __restrict__ Bbase, int bstride,
    float* __restrict__ Cbase, int cstride,
    int M, int N, int K) {
  __shared__ unsigned short As[64 * 64];
  __shared__ unsigned short Bs[64 * 64];

  const unsigned short* B = Bbase + (size_t)blockIdx.z * bstride;
  float* C = Cbase + (size_t)blockIdx.z * cstride;

  const int row0 = blockIdx.y * 64;
  const int col0 = blockIdx.x * 64;
  const int tid  = threadIdx.x;
  const int lane = tid & 63;
  const int w    = tid >> 6;       // wave id 0..3
  const int wr   = w >> 1;         // wave row 0..1
  const int wc   = w & 1;          // wave col 0..1
  const int quad = lane >> 4;      // 0..3
  const int lc   = lane & 15;

  // staging map: thread -> (row srow, 16B granule tid&7), covers 32 rows/pass
  const int srow = tid >> 3;
  const int sg   = tid & 7;                    // granule within row
  const int scol = sg * 8;                     // element col in global tile
  const int sw0  = (sg ^ (srow & 7)) * 8;      // swizzled LDS elem col

  floatx4 acc[2][2] = {};

  for (int k0 = 0; k0 < K; k0 += 64) {
    short8 a0 = *(const short8*)&Abf[(size_t)(row0 + srow) * K + k0 + scol];
    short8 a1 = *(const short8*)&Abf[(size_t)(row0 + srow + 32) * K + k0 + scol];
    short8 b0 = *(const short8*)&B[(size_t)(col0 + srow) * K + k0 + scol];
    short8 b1 = *(const short8*)&B[(size_t)(col0 + srow + 32) * K + k0 + scol];
    __syncthreads();   // previous iteration's LDS reads complete
    *(short8*)&As[srow * 64 + sw0] = a0;
    *(short8*)&As[(srow + 32) * 64 + sw0] = a1;   // (srow+32)&7 == srow&7
    *(short8*)&Bs[srow * 64 + sw0] = b0;
    *(short8*)&Bs[(srow + 32) * 64 + sw0] = b1;
    __syncthreads();

#pragma unroll
    for (int s = 0; s < 2; ++s) {
      const int gk = s * 4 + quad;            // k-granule 0..7
      short8 aF[2], bF[2];
#pragma unroll
      for (int i = 0; i < 2; ++i) {
        int m = wr * 32 + i * 16 + lc;
        aF[i] = *(const short8*)&As[m * 64 + (gk ^ (m & 7)) * 8];
      }
#pragma unroll
      for (int j = 0; j < 2; ++j) {
        int n = wc * 32 + j * 16 + lc;
        bF[j] = *(const short8*)&Bs[n * 64 + (gk ^ (n & 7)) * 8];
      }
#pragma unroll
      for (int i = 0; i < 2; ++i)
#pragma unroll
        for (int j = 0; j < 2; ++j)
          acc[i][j] = __builtin_amdgcn_mfma_f32_16x16x32_bf16(
              aF[i], bF[j], acc[i][j], 0, 0, 0);
    }
  }

  // C/D layout: col = lane&15, row = quad*4 + reg  [verified m89/m91]
#pragma unroll
  for (int i = 0; i < 2; ++i)
#pragma unroll
    for (int j = 0; j < 2; ++j) {
      int col = col0 + wc * 32 + j * 16 + lc;
#pragma unroll
      for (int r = 0; r < 4; ++r) {
        int row = row0 + wr * 32 + i * 16 + quad * 4 + r;
        C[(size_t)row * N + col] = acc[i][j][r];
      }
    }
}

// ---------------------------------------------------------------------------
// Sliding-window per-channel softmax (shift-invariant: no max subtraction,
// |s| <= ~6 so exp is safe in fp32). 64 independent exps, 4-way acc chains.
// One thread per (i, c); writes bf16 for the output projection GEMM.
// ---------------------------------------------------------------------------
__global__ __launch_bounds__(256) void swin_attn(
    const float* __restrict__ q, const float* __restrict__ k,
    const float* __restrict__ v, unsigned short* __restrict__ o) {
  const int gid = blockIdx.x * 256 + threadIdx.x;
  const int i = gid >> 9;          // row
  const int c = gid & 511;         // channel
  const float qv = q[gid] * ATTN_SCALE;
  const int jbase = i - (WIN - 1);

  float l0 = 0.f, l1 = 0.f, l2 = 0.f, l3 = 0.f;
  float a0 = 0.f, a1 = 0.f, a2 = 0.f, a3 = 0.f;

#pragma unroll 4
  for (int t = 0; t < WIN; t += 4) {
#pragma unroll
    for (int u = 0; u < 4; ++u) {
      const int j = jbase + t + u;
      const int jc = j < 0 ? 0 : j;
      const float kv = k[(size_t)jc * DM + c];
      const float vv = v[(size_t)jc * DM + c];
      float p = __expf(qv * kv);
      p = (j >= 0) ? p : 0.f;
      const float pv = p * vv;
      if (u == 0)      { l0 += p; a0 += pv; }
      else if (u == 1) { l1 += p; a1 += pv; }
      else if (u == 2) { l2 += p; a2 += pv; }
      else             { l3 += p; a3 += pv; }
    }
  }
  const float out = (a0 + a1 + a2 + a3) / (l0 + l1 + l2 + l3);
  o[gid] = f2bf(out);
}

// ---------------------------------------------------------------------------
// Launch
// ---------------------------------------------------------------------------
extern "C" void kernel_launch(void* const* d_in, const int* in_sizes, int n_in,
                              void* d_out, int out_size, void* d_ws, size_t ws_size,
                              hipStream_t stream) {
  const float* x  = (const float*)d_in[0];
  const float* Wq = (const float*)d_in[1];
  const float* Wk = (const float*)d_in[2];
  const float* Wv = (const float*)d_in[3];
  const float* Wo = (const float*)d_in[4];
  float* out = (float*)d_out;

  // ws layout (16 MB total):
  //   q, k, v : 3 x 1M fp32 (12 MB)
  //   xbf     : 1M bf16 (2 MB)  -- reused as attn_bf16 after qkv GEMM
  //   wbf     : 4 x 256K bf16 (2 MB)
  float* q = (float*)d_ws;
  float* kk = q + (size_t)S * DM;
  float* vv = kk + (size_t)S * DM;
  unsigned short* xbf = (unsigned short*)(vv + (size_t)S * DM);
  unsigned short* wbf = xbf + (size_t)S * DM;
  unsigned short* attnbf = xbf;   // reuse after x is consumed

  // 1) fp32 -> bf16 conversions (2M elements, 4/thread)
  convert_bf16<<<dim3(2048), dim3(256), 0, stream>>>(x, Wq, Wk, Wv, Wo, xbf, wbf);

  // 2) fused QKV: C_z = x * W_z^T, z = 0,1,2
  gemm_bf16<<<dim3(DM / 64, S / 64, 3), dim3(256), 0, stream>>>(
      xbf, wbf, DM * DM, q, S * DM, S, DM, DM);

  // 3) sliding-window per-channel softmax -> bf16
  swin_attn<<<dim3(S * DM / 256), dim3(256), 0, stream>>>(q, kk, vv, attnbf);

  // 4) output projection: out = attn * Wo^T
  gemm_bf16<<<dim3(DM / 64, S / 64, 1), dim3(256), 0, stream>>>(
      attnbf, wbf + 3 * (size_t)DM * DM, 0, out, 0, S, DM, DM);
}